// Round 12
// baseline (94.172 us; speedup 1.0000x reference)
//
#include <hip/hip_runtime.h>

#define B_N 8192
#define C_N 20000
#define D_N 128
#define CPAD 20096              // 314 * 64
#define NPAD 96
#define NTILES64 314            // 64-row center tiles
#define NCHUNK 16               // tiles strided: tile = chunk + 16*j ; 16*32=512 blocks = 2/CU
#define MARGIN_F 0.15001125f    // 0.15 + (1/40000)*(0.6-0.15)

#define NORM_BLOCKS 1024        // 8 rows per block (4 waves x 2 rows)
#define CONV_BLOCKS 2512        // CPAD*128/4/256

typedef __attribute__((ext_vector_type(8))) short bf16x8;
typedef __attribute__((ext_vector_type(4))) float f32x4;

typedef __attribute__((address_space(1))) const unsigned int GUint;
typedef __attribute__((address_space(3))) unsigned int LUint;

__device__ __forceinline__ unsigned short f2bf(float x) {
    union { float f; unsigned int u; } v; v.f = x;
    unsigned int r = v.u + 0x7fffu + ((v.u >> 16) & 1u);
    return (unsigned short)(r >> 16);
}
__device__ __forceinline__ float bf2f(unsigned short h) {
    union { unsigned int u; float f; } v; v.u = ((unsigned int)h) << 16; return v.f;
}

// ---- kernel 1 (fused prep): blocks [0,1024) normalize features (float4, 2
// rows/wave); rest convert centers -> bf16 (zero-padded). Per-row corrections
// for the max-identity accounting:
//   S_valid = M + CPAD*sum(t) - sum_f[relu(t+pb)] - NPAD*sum_f[relu(t)]
//   C_valid = C_all - sum_f[1(t+pb>0)] - NPAD*sum_f[1(t>0)]
__global__ __launch_bounds__(256) void k_prep(
    const float* __restrict__ feat, const float* __restrict__ centers,
    const int* __restrict__ labels, unsigned short* __restrict__ fb,
    unsigned short* __restrict__ cb, float* __restrict__ t,
    float* __restrict__ corr_s, unsigned int* __restrict__ corr_c)
{
    const int bid = blockIdx.x;
    if (bid < NORM_BLOCKS) {
        const int lane = threadIdx.x & 63;
        const int l32  = lane & 31;
        const int row  = bid * 8 + ((threadIdx.x >> 6) << 1) + (lane >> 5);
        const float4 fv = *(const float4*)(feat + (size_t)row * D_N + l32 * 4);
        float ss = fv.x * fv.x + fv.y * fv.y + fv.z * fv.z + fv.w * fv.w;
        #pragma unroll
        for (int off = 16; off; off >>= 1) ss += __shfl_xor(ss, off);
        const float scale = 1.0f / fmaxf(sqrtf(ss), 1e-12f);
        const float a0 = fv.x * scale, a1 = fv.y * scale;
        const float a2 = fv.z * scale, a3 = fv.w * scale;
        ushort4 o; o.x = f2bf(a0); o.y = f2bf(a1); o.z = f2bf(a2); o.w = f2bf(a3);
        *(ushort4*)(fb + (size_t)row * D_N + l32 * 4) = o;

        const int lab = labels[row];
        const float4 cv = *(const float4*)(centers + (size_t)lab * D_N + l32 * 4);
        float pd = a0 * cv.x + a1 * cv.y + a2 * cv.z + a3 * cv.w;       // fp32 dot
        float pb = bf2f(o.x) * bf2f(f2bf(cv.x)) + bf2f(o.y) * bf2f(f2bf(cv.y))
                 + bf2f(o.z) * bf2f(f2bf(cv.z)) + bf2f(o.w) * bf2f(f2bf(cv.w));
        #pragma unroll
        for (int off = 16; off; off >>= 1) {
            pd += __shfl_xor(pd, off);
            pb += __shfl_xor(pb, off);
        }
        if (l32 == 0) {
            const float tb = MARGIN_F - pd;
            t[row] = tb;
            corr_s[row] = fmaxf(tb + pb, 0.0f) + (float)NPAD * fmaxf(tb, 0.0f);
            corr_c[row] = ((tb + pb > 0.0f) ? 1u : 0u) + ((tb > 0.0f) ? (unsigned)NPAD : 0u);
        }
    } else {
        const int idx = (bid - NORM_BLOCKS) * 256 + threadIdx.x;
        const int e = idx * 4;
        const int row = e >> 7;
        ushort4 o;
        if (row < C_N) {
            const float4 v = *(const float4*)(centers + e);
            o.x = f2bf(v.x); o.y = f2bf(v.y); o.z = f2bf(v.z); o.w = f2bf(v.w);
        } else {
            o.x = 0; o.y = 0; o.z = 0; o.w = 0;
        }
        *(ushort4*)(cb + e) = o;
    }
}

// ---- kernel 2: main. Wave tile 128 feat x 32 cent: 64 MFMA (1242 cyc of
// matrix-pipe work) per 8 ds_read_b128 — doubles pipe work per LDS transaction
// vs R11 and halves block-level LDS read redundancy (2 waves share a center
// row, was 4). 4 waves = 2 featgroups x 2 centgroups; block tile 256f x 64c.
// __launch_bounds__(256,2): 256-VGPR budget fits ffr128+acc64+misc (~225).
// Max-identity epilogue (R11-proven): acc zero-init via MFMA C-operand,
// M = sum max(d,-t), 3 VALU/elem + SALU count.
__global__ __launch_bounds__(256, 2) void k_main(
    const unsigned short* __restrict__ fb,   // [8192][128] bf16 normalized features
    const unsigned short* __restrict__ cb,   // [20096][128] bf16 centers, zero-padded
    const float* __restrict__ t,             // [8192]
    float* __restrict__ acc_slots)           // 4 x {M, cnt} slots, 64B apart
{
    __shared__ __align__(16) unsigned short sB[2][64 * 128];   // 2 x 16 KB
    __shared__ float sWsum[4];
    __shared__ unsigned int sWcnt[4];

    const int tid  = threadIdx.x;
    const int lane = tid & 63;
    const int w    = tid >> 6;            // wave 0..3
    const int fg   = w >> 1;              // feature group (0,1)
    const int cg   = w & 1;               // center group (0,1)
    const int chunk   = blockIdx.x;       // 0..15, tiles chunk + 16*j
    const int rowbase = blockIdx.y * 256; // feature row block
    const int nt = (NTILES64 - 1 - chunk) / NCHUNK + 1;  // 20 (chunk<10) else 19

    const int l15 = lane & 15;
    const int kg  = lane >> 4;

    // ---- feature fragments + NEGATED t -> registers (block-lifetime) ----
    bf16x8 ffr[4][8];                     // [ks][ff]  = 128 VGPRs
    float ntv[8];
    #pragma unroll
    for (int ff = 0; ff < 8; ++ff) {
        const int m = rowbase + fg * 128 + ff * 16 + l15;
        const unsigned short* src = fb + (size_t)m * D_N + kg * 8;
        #pragma unroll
        for (int ks = 0; ks < 4; ++ks)
            ffr[ks][ff] = *(const bf16x8*)(src + ks * 32);
        ntv[ff] = -t[m];
    }

    const f32x4 zero4 = {0.0f, 0.0f, 0.0f, 0.0f};   // pinned C-operand

    // ---- center staging: tile = 64 rows x 256 B = 16 KB = 4 loads/thread.
    // Linear LDS dest + involution-swizzled global source (proven pattern).
    const char* gB0 = (const char*)cb;
    auto STAGE = [&](int buf, int tile) {
        const char* gB = gB0 + (size_t)tile * 16384;
        #pragma unroll
        for (int i = 0; i < 4; ++i) {
            const int loff = i * 4096 + w * 1024;          // wave-uniform LDS base
            const int x = loff + lane * 16;
            const int sx = x ^ (((x >> 8) & 7) << 4);      // involution
            __builtin_amdgcn_global_load_lds((GUint*)(gB + sx),
                (LUint*)((char*)sB[buf] + loff), 16, 0, 0);
        }
    };

    STAGE(0, chunk);
    __syncthreads();

    float ls[4] = {0.0f, 0.0f, 0.0f, 0.0f};
    unsigned int wcnt = 0;

    for (int j = 0; j < nt; ++j) {
        const int cur = j & 1;
        if (j + 1 < nt) STAGE(cur ^ 1, chunk + (j + 1) * NCHUNK);  // prefetch first

        const char* sbase = (const char*)sB[cur];
        f32x4 acc[2][8];                  // [fc][ff] raw dots = 64 VGPRs
        #pragma unroll
        for (int ks = 0; ks < 4; ++ks) {
            bf16x8 cfr[2];
            #pragma unroll
            for (int fc = 0; fc < 2; ++fc) {
                const int row = cg * 32 + fc * 16 + l15;       // center row in tile
                int p = row * 256 + ks * 64 + kg * 16;
                p ^= ((row & 7) << 4);
                cfr[fc] = *(const bf16x8*)(sbase + p);
            }
            if (ks == 0) {
                #pragma unroll
                for (int fc = 0; fc < 2; ++fc)
                    #pragma unroll
                    for (int ff = 0; ff < 8; ++ff)
                        acc[fc][ff] = __builtin_amdgcn_mfma_f32_16x16x32_bf16(
                            cfr[fc], ffr[0][ff], zero4, 0, 0, 0);   // overwrite-init
            } else {
                #pragma unroll
                for (int fc = 0; fc < 2; ++fc)
                    #pragma unroll
                    for (int ff = 0; ff < 8; ++ff)
                        acc[fc][ff] = __builtin_amdgcn_mfma_f32_16x16x32_bf16(
                            cfr[fc], ffr[ks][ff], acc[fc][ff], 0, 0, 0);
            }
        }

        // epilogue: 3 VALU/elem (v_max, v_add, v_cmp->sgpr) + SALU count
        #pragma unroll
        for (int fc = 0; fc < 2; ++fc)
            #pragma unroll
            for (int ff = 0; ff < 8; ++ff)
                #pragma unroll
                for (int r = 0; r < 4; ++r) {
                    const float d = acc[fc][ff][r];
                    ls[fc * 2 + (ff & 1)] += fmaxf(d, ntv[ff]);
                    wcnt += (unsigned int)__popcll(__ballot(d > ntv[ff]));
                }

        __syncthreads();   // drains prefetch vmcnt; read buffer freed
    }

    float lsum = (ls[0] + ls[1]) + (ls[2] + ls[3]);
    #pragma unroll
    for (int off = 32; off; off >>= 1) lsum += __shfl_xor(lsum, off);
    if (lane == 0) { sWsum[w] = lsum; sWcnt[w] = wcnt; }
    __syncthreads();
    if (tid == 0) {
        float s = 0.0f; unsigned int c = 0;
        #pragma unroll
        for (int i = 0; i < 4; ++i) { s += sWsum[i]; c += sWcnt[i]; }
        const int slot = (blockIdx.x ^ blockIdx.y) & 3;        // spread atomics
        atomicAdd(acc_slots + slot * 16, s);
        atomicAdd((unsigned int*)(acc_slots + slot * 16 + 1), c);
    }
}

// ---- kernel 3: reduce corrections + t-sum + slots, finalize in double ----
__global__ __launch_bounds__(256) void k_finalize(
    const float* __restrict__ acc_slots, const float* __restrict__ t,
    const float* __restrict__ corr_s, const unsigned int* __restrict__ corr_c,
    float* __restrict__ out)
{
    __shared__ float ss[4], st[4];
    __shared__ unsigned int sc[4];
    const int tid = threadIdx.x;
    const int lane = tid & 63;
    const int w = tid >> 6;
    float cs = 0.0f, ct = 0.0f; unsigned int cc = 0;
    for (int i = tid; i < B_N; i += 256) {
        cs += corr_s[i]; ct += t[i]; cc += corr_c[i];
    }
    #pragma unroll
    for (int off = 32; off; off >>= 1) {
        cs += __shfl_xor(cs, off);
        ct += __shfl_xor(ct, off);
        cc += __shfl_xor(cc, off);
    }
    if (lane == 0) { ss[w] = cs; st[w] = ct; sc[w] = cc; }
    __syncthreads();
    if (tid == 0) {
        const double CS = (double)ss[0] + ss[1] + ss[2] + ss[3];
        const double CT = (double)st[0] + st[1] + st[2] + st[3];
        const long long CC = (long long)sc[0] + sc[1] + sc[2] + sc[3];
        double M = 0.0; long long Call = 0;
        #pragma unroll
        for (int i = 0; i < 4; ++i) {
            M += (double)acc_slots[i * 16];
            Call += (long long)((const unsigned int*)acc_slots)[i * 16 + 1];
        }
        const double S = M + (double)CPAD * CT - CS;
        const long long C = Call - CC;
        out[0] = (C > 0) ? (float)(S / (double)C) : 0.0f;
    }
}

extern "C" void kernel_launch(void* const* d_in, const int* in_sizes, int n_in,
                              void* d_out, int out_size, void* d_ws, size_t ws_size,
                              hipStream_t stream) {
    const float* feat    = (const float*)d_in[0];
    const float* centers = (const float*)d_in[1];
    const int*   labels  = (const int*)d_in[2];
    float* out = (float*)d_out;

    char* ws = (char*)d_ws;
    float*          acc_slots = (float*)ws;                          // 256 B (4 x 64B)
    float*          t         = (float*)(ws + 1024);                 // 32 KB
    float*          corr_s    = (float*)(ws + 65536);                // 32 KB
    unsigned int*   corr_c    = (unsigned int*)(ws + 98304);         // 32 KB
    unsigned short* fb        = (unsigned short*)(ws + 131072);      // 2 MB
    unsigned short* cb        = (unsigned short*)(ws + 4*1024*1024); // 5.14 MB

    hipMemsetAsync(ws, 0, 256, stream);
    k_prep<<<NORM_BLOCKS + CONV_BLOCKS, 256, 0, stream>>>(
        feat, centers, labels, fb, cb, t, corr_s, corr_c);
    dim3 grid(NCHUNK, 32);
    k_main<<<grid, 256, 0, stream>>>(fb, cb, t, acc_slots);
    k_finalize<<<1, 256, 0, stream>>>(acc_slots, t, corr_s, corr_c, out);
}

// Round 14
// 78.800 us; speedup vs baseline: 1.1951x; 1.1951x over previous
//
#include <hip/hip_runtime.h>

#define B_N 8192
#define C_N 20000
#define D_N 128
#define CPAD 20096              // 628 * 32
#define NPAD 96
#define NTILES32 628            // 32-row center tiles
#define NCHUNK 24               // tiles strided: tile = chunk + 24*j ; 24*32=768 blocks = 3/CU
#define MARGIN_F 0.15001125f    // 0.15 + (1/40000)*(0.6-0.15)

#define NORM_BLOCKS 1024        // 8 rows per block (4 waves x 2 rows)
#define CONV_BLOCKS 2512        // CPAD*128/4/256

typedef __attribute__((ext_vector_type(8))) short bf16x8;
typedef __attribute__((ext_vector_type(4))) float f32x4;

typedef __attribute__((address_space(1))) const unsigned int GUint;
typedef __attribute__((address_space(3))) unsigned int LUint;

__device__ __forceinline__ unsigned short f2bf(float x) {
    union { float f; unsigned int u; } v; v.f = x;
    unsigned int r = v.u + 0x7fffu + ((v.u >> 16) & 1u);
    return (unsigned short)(r >> 16);
}
__device__ __forceinline__ float bf2f(unsigned short h) {
    union { unsigned int u; float f; } v; v.u = ((unsigned int)h) << 16; return v.f;
}

// ---- kernel 1 (fused prep): blocks [0,1024) normalize features (float4, 2
// rows/wave); rest convert centers -> bf16 (zero-padded). Per-row corrections
// for the max-identity accounting:
//   S_valid = M + CPAD*sum(t) - sum_f[relu(t+pb)] - NPAD*sum_f[relu(t)]
//   C_valid = C_all - sum_f[1(t+pb>0)] - NPAD*sum_f[1(t>0)]
__global__ __launch_bounds__(256) void k_prep(
    const float* __restrict__ feat, const float* __restrict__ centers,
    const int* __restrict__ labels, unsigned short* __restrict__ fb,
    unsigned short* __restrict__ cb, float* __restrict__ t,
    float* __restrict__ corr_s, unsigned int* __restrict__ corr_c)
{
    const int bid = blockIdx.x;
    if (bid < NORM_BLOCKS) {
        const int lane = threadIdx.x & 63;
        const int l32  = lane & 31;
        const int row  = bid * 8 + ((threadIdx.x >> 6) << 1) + (lane >> 5);
        const float4 fv = *(const float4*)(feat + (size_t)row * D_N + l32 * 4);
        float ss = fv.x * fv.x + fv.y * fv.y + fv.z * fv.z + fv.w * fv.w;
        #pragma unroll
        for (int off = 16; off; off >>= 1) ss += __shfl_xor(ss, off);
        const float scale = 1.0f / fmaxf(sqrtf(ss), 1e-12f);
        const float a0 = fv.x * scale, a1 = fv.y * scale;
        const float a2 = fv.z * scale, a3 = fv.w * scale;
        ushort4 o; o.x = f2bf(a0); o.y = f2bf(a1); o.z = f2bf(a2); o.w = f2bf(a3);
        *(ushort4*)(fb + (size_t)row * D_N + l32 * 4) = o;

        const int lab = labels[row];
        const float4 cv = *(const float4*)(centers + (size_t)lab * D_N + l32 * 4);
        float pd = a0 * cv.x + a1 * cv.y + a2 * cv.z + a3 * cv.w;       // fp32 dot
        float pb = bf2f(o.x) * bf2f(f2bf(cv.x)) + bf2f(o.y) * bf2f(f2bf(cv.y))
                 + bf2f(o.z) * bf2f(f2bf(cv.z)) + bf2f(o.w) * bf2f(f2bf(cv.w));
        #pragma unroll
        for (int off = 16; off; off >>= 1) {
            pd += __shfl_xor(pd, off);
            pb += __shfl_xor(pb, off);
        }
        if (l32 == 0) {
            const float tb = MARGIN_F - pd;
            t[row] = tb;
            corr_s[row] = fmaxf(tb + pb, 0.0f) + (float)NPAD * fmaxf(tb, 0.0f);
            corr_c[row] = ((tb + pb > 0.0f) ? 1u : 0u) + ((tb > 0.0f) ? (unsigned)NPAD : 0u);
        }
    } else {
        const int idx = (bid - NORM_BLOCKS) * 256 + threadIdx.x;
        const int e = idx * 4;
        const int row = e >> 7;
        ushort4 o;
        if (row < C_N) {
            const float4 v = *(const float4*)(centers + e);
            o.x = f2bf(v.x); o.y = f2bf(v.y); o.z = f2bf(v.z); o.w = f2bf(v.w);
        } else {
            o.x = 0; o.y = 0; o.z = 0; o.w = 0;
        }
        *(ushort4*)(cb + e) = o;
    }
}

// ---- kernel 2: main. R11 body + software-pipelined epilogue: two named acc
// sets (accA/accB); the epilogue of tile j-1 is interleaved into tile j's MFMA
// cluster in 8-element slices (independent regs -> rides in MFMA issue shadow).
// All 8 ds_read_b128 hoisted ahead of the cluster (one lgkm wait per tile).
__global__ __launch_bounds__(256, 3) void k_main(
    const unsigned short* __restrict__ fb,   // [8192][128] bf16 normalized features
    const unsigned short* __restrict__ cb,   // [20096][128] bf16 centers, zero-padded
    const float* __restrict__ t,             // [8192]
    float* __restrict__ acc_slots)           // 4 x {M, cnt} slots, 64B apart
{
    __shared__ __align__(16) unsigned short sB[2][32 * 128];   // 2 x 8 KB
    __shared__ float sWsum[4];
    __shared__ unsigned int sWcnt[4];

    const int tid  = threadIdx.x;
    const int lane = tid & 63;
    const int w    = tid >> 6;            // wave 0..3
    const int chunk   = blockIdx.x;       // 0..23, tiles chunk + 24*j
    const int rowbase = blockIdx.y * 256; // feature row block
    const int nt = (NTILES32 - 1 - chunk) / NCHUNK + 1;  // 27 (chunk<4) else 26

    const int wf = w * 64;                // wave feature offset
    const int l15 = lane & 15;
    const int kg  = lane >> 4;

    // ---- feature fragments + NEGATED t -> registers (block-lifetime) ----
    bf16x8 ffr[4][4];                     // [ks][ff]
    float ntv[4];
    #pragma unroll
    for (int ff = 0; ff < 4; ++ff) {
        const int m = rowbase + wf + ff * 16 + l15;
        const unsigned short* src = fb + (size_t)m * D_N + kg * 8;
        #pragma unroll
        for (int ks = 0; ks < 4; ++ks)
            ffr[ks][ff] = *(const bf16x8*)(src + ks * 32);
        ntv[ff] = -t[m];
    }

    const f32x4 zero4 = {0.0f, 0.0f, 0.0f, 0.0f};   // pinned C-operand

    // ---- center staging: linear LDS dest + involution-swizzled global source ----
    const char* gB0 = (const char*)cb;
    auto STAGE = [&](int buf, int tile) {
        const char* gB = gB0 + (size_t)tile * 8192;
        #pragma unroll
        for (int i = 0; i < 2; ++i) {
            const int loff = w * 1024 + i * 4096;          // wave-uniform LDS base
            const int x = loff + lane * 16;
            const int sx = x ^ (((x >> 8) & 7) << 4);      // involution
            __builtin_amdgcn_global_load_lds((GUint*)(gB + sx),
                (LUint*)((char*)sB[buf] + loff), 16, 0, 0);
        }
    };

    float ls[4] = {0.0f, 0.0f, 0.0f, 0.0f};
    unsigned int wcnt = 0;

    f32x4 accA[2][4], accB[2][4];         // two named sets (no dynamic indexing)

// one 8-element epilogue slice (ff = S) of the PREVIOUS tile's accumulator
#define EPI_SLICE(P, S)                                                 \
    _Pragma("unroll")                                                   \
    for (int fc = 0; fc < 2; ++fc)                                      \
        _Pragma("unroll")                                               \
        for (int r = 0; r < 4; ++r) {                                   \
            const float d_ = P[fc][S][r];                               \
            ls[fc * 2 + ((S) & 1)] += fmaxf(d_, ntv[S]);                \
            wcnt += (unsigned int)__popcll(__ballot(d_ > ntv[S]));      \
        }

#define EPI_ALL(P) { EPI_SLICE(P, 0) EPI_SLICE(P, 1) EPI_SLICE(P, 2) EPI_SLICE(P, 3) }

// tile body: stage j+1, hoisted ds_reads, MFMA cluster with interleaved
// epilogue slices of PREV (compile-time DO_EPI), trailing barrier.
#define TILE_BODY(J, ACC, PREV, DO_EPI)                                 \
    {                                                                   \
        const int cur_ = (J) & 1;                                       \
        if ((J) + 1 < nt) STAGE(cur_ ^ 1, chunk + ((J) + 1) * NCHUNK);  \
        const char* sbase_ = (const char*)sB[cur_];                     \
        bf16x8 cfr[4][2];                                               \
        _Pragma("unroll")                                               \
        for (int ks = 0; ks < 4; ++ks)                                  \
            _Pragma("unroll")                                           \
            for (int fc = 0; fc < 2; ++fc) {                            \
                const int row_ = fc * 16 + l15;                         \
                int p_ = row_ * 256 + ks * 64 + kg * 16;                \
                p_ ^= ((row_ & 7) << 4);                                \
                cfr[ks][fc] = *(const bf16x8*)(sbase_ + p_);            \
            }                                                           \
        _Pragma("unroll")                                               \
        for (int fc = 0; fc < 2; ++fc)                                  \
            _Pragma("unroll")                                           \
            for (int ff = 0; ff < 4; ++ff)                              \
                ACC[fc][ff] = __builtin_amdgcn_mfma_f32_16x16x32_bf16(  \
                    cfr[0][fc], ffr[0][ff], zero4, 0, 0, 0);            \
        if (DO_EPI) { EPI_SLICE(PREV, 0) }                              \
        _Pragma("unroll")                                               \
        for (int fc = 0; fc < 2; ++fc)                                  \
            _Pragma("unroll")                                           \
            for (int ff = 0; ff < 4; ++ff)                              \
                ACC[fc][ff] = __builtin_amdgcn_mfma_f32_16x16x32_bf16(  \
                    cfr[1][fc], ffr[1][ff], ACC[fc][ff], 0, 0, 0);      \
        if (DO_EPI) { EPI_SLICE(PREV, 1) }                              \
        _Pragma("unroll")                                               \
        for (int fc = 0; fc < 2; ++fc)                                  \
            _Pragma("unroll")                                           \
            for (int ff = 0; ff < 4; ++ff)                              \
                ACC[fc][ff] = __builtin_amdgcn_mfma_f32_16x16x32_bf16(  \
                    cfr[2][fc], ffr[2][ff], ACC[fc][ff], 0, 0, 0);      \
        if (DO_EPI) { EPI_SLICE(PREV, 2) }                              \
        _Pragma("unroll")                                               \
        for (int fc = 0; fc < 2; ++fc)                                  \
            _Pragma("unroll")                                           \
            for (int ff = 0; ff < 4; ++ff)                              \
                ACC[fc][ff] = __builtin_amdgcn_mfma_f32_16x16x32_bf16(  \
                    cfr[3][fc], ffr[3][ff], ACC[fc][ff], 0, 0, 0);      \
        if (DO_EPI) { EPI_SLICE(PREV, 3) }                              \
        __syncthreads();                                                \
    }

    STAGE(0, chunk);
    __syncthreads();

    TILE_BODY(0, accA, accB, 0)           // fill accA, no previous epilogue
    int j = 1;
    for (; j + 1 < nt; j += 2) {
        TILE_BODY(j,     accB, accA, 1)   // compute B, finish A
        TILE_BODY(j + 1, accA, accB, 1)   // compute A, finish B
    }
    if (j < nt) {                         // nt even: one leftover tile
        TILE_BODY(j, accB, accA, 1)
        EPI_ALL(accB)
    } else {                              // nt odd: accA holds the last tile
        EPI_ALL(accA)
    }

#undef TILE_BODY
#undef EPI_ALL
#undef EPI_SLICE

    float lsum = (ls[0] + ls[1]) + (ls[2] + ls[3]);
    #pragma unroll
    for (int off = 32; off; off >>= 1) lsum += __shfl_xor(lsum, off);
    if (lane == 0) { sWsum[w] = lsum; sWcnt[w] = wcnt; }
    __syncthreads();
    if (tid == 0) {
        float s = 0.0f; unsigned int c = 0;
        #pragma unroll
        for (int i = 0; i < 4; ++i) { s += sWsum[i]; c += sWcnt[i]; }
        const int slot = (blockIdx.x ^ blockIdx.y) & 3;        // spread atomics
        atomicAdd(acc_slots + slot * 16, s);
        atomicAdd((unsigned int*)(acc_slots + slot * 16 + 1), c);
    }
}

// ---- kernel 3: reduce corrections + t-sum + slots, finalize in double ----
__global__ __launch_bounds__(256) void k_finalize(
    const float* __restrict__ acc_slots, const float* __restrict__ t,
    const float* __restrict__ corr_s, const unsigned int* __restrict__ corr_c,
    float* __restrict__ out)
{
    __shared__ float ss[4], st[4];
    __shared__ unsigned int sc[4];
    const int tid = threadIdx.x;
    const int lane = tid & 63;
    const int w = tid >> 6;
    float cs = 0.0f, ct = 0.0f; unsigned int cc = 0;
    for (int i = tid; i < B_N; i += 256) {
        cs += corr_s[i]; ct += t[i]; cc += corr_c[i];
    }
    #pragma unroll
    for (int off = 32; off; off >>= 1) {
        cs += __shfl_xor(cs, off);
        ct += __shfl_xor(ct, off);
        cc += __shfl_xor(cc, off);
    }
    if (lane == 0) { ss[w] = cs; st[w] = ct; sc[w] = cc; }
    __syncthreads();
    if (tid == 0) {
        const double CS = (double)ss[0] + ss[1] + ss[2] + ss[3];
        const double CT = (double)st[0] + st[1] + st[2] + st[3];
        const long long CC = (long long)sc[0] + sc[1] + sc[2] + sc[3];
        double M = 0.0; long long Call = 0;
        #pragma unroll
        for (int i = 0; i < 4; ++i) {
            M += (double)acc_slots[i * 16];
            Call += (long long)((const unsigned int*)acc_slots)[i * 16 + 1];
        }
        const double S = M + (double)CPAD * CT - CS;
        const long long C = Call - CC;
        out[0] = (C > 0) ? (float)(S / (double)C) : 0.0f;
    }
}

extern "C" void kernel_launch(void* const* d_in, const int* in_sizes, int n_in,
                              void* d_out, int out_size, void* d_ws, size_t ws_size,
                              hipStream_t stream) {
    const float* feat    = (const float*)d_in[0];
    const float* centers = (const float*)d_in[1];
    const int*   labels  = (const int*)d_in[2];
    float* out = (float*)d_out;

    char* ws = (char*)d_ws;
    float*          acc_slots = (float*)ws;                          // 256 B (4 x 64B)
    float*          t         = (float*)(ws + 1024);                 // 32 KB
    float*          corr_s    = (float*)(ws + 65536);                // 32 KB
    unsigned int*   corr_c    = (unsigned int*)(ws + 98304);         // 32 KB
    unsigned short* fb        = (unsigned short*)(ws + 131072);      // 2 MB
    unsigned short* cb        = (unsigned short*)(ws + 4*1024*1024); // 5.14 MB

    hipMemsetAsync(ws, 0, 256, stream);
    k_prep<<<NORM_BLOCKS + CONV_BLOCKS, 256, 0, stream>>>(
        feat, centers, labels, fb, cb, t, corr_s, corr_c);
    dim3 grid(NCHUNK, 32);
    k_main<<<grid, 256, 0, stream>>>(fb, cb, t, acc_slots);
    k_finalize<<<1, 256, 0, stream>>>(acc_slots, t, corr_s, corr_c, out);
}